// Round 3
// baseline (390.686 us; speedup 1.0000x reference)
//
#include <hip/hip_runtime.h>

#define EPS 1e-6f

constexpr int KNB = 32;            // K neighbors
constexpr int NFG = 4;
constexpr int NH  = 16;
constexpr int NFO = 32;
constexpr int FH  = NFG * NH;      // 64
constexpr int ACN = KNB * FH;      // 2048 ac elems per row
constexpr int ON  = NFO * NH;      // 512 output elems per row
constexpr int KN  = KNB * NH;      // 512 attn elems per row
constexpr int ROWSTRIDE = KNB * ON; // 16384 floats of node_out per row

// ---------------- K1: per-row attention weights ----------------
__global__ __launch_bounds__(256, 4)
void attn_weights(const float* __restrict__ beta,
                  const float* __restrict__ sa,
                  const float* __restrict__ ac,
                  const float* __restrict__ gw,
                  float* __restrict__ attn_out)  // [BL, 512]
{
    const int bl   = blockIdx.x;
    const int tid  = threadIdx.x;
    const int lane = tid & 63;
    const int wv   = tid >> 6;

    __shared__ float s_ac[ACN];
    __shared__ float s_gw[KNB * NFG];
    __shared__ float s_bg[FH];
    __shared__ float s_wm[4 * NH];
    __shared__ float s_wd[4 * NH];

    const size_t blz = (size_t)bl;
    const float* acp = ac + blz * ACN;

    if (tid < FH)        s_bg[tid] = beta[blz * FH + tid] + EPS;
    if (tid < KNB * NFG) s_gw[tid] = gw[blz * (KNB * NFG) + tid];
    __syncthreads();

    const int h = tid & 15;

    float lmax = -INFINITY;
    #pragma unroll
    for (int j = 0; j < 8; ++j) {
        const int idx = tid + j * 256;
        float v = acp[idx];
        if (j == 0 && tid < FH) v += sa[blz * FH + tid];  // k==0 slot
        v *= s_bg[idx & 63];
        s_ac[idx] = v;
        lmax = fmaxf(lmax, v);
    }

    lmax = fmaxf(lmax, __shfl_xor(lmax, 16, 64));
    lmax = fmaxf(lmax, __shfl_xor(lmax, 32, 64));
    if (lane < 16) s_wm[wv * 16 + lane] = lmax;
    __syncthreads();
    const float m = fmaxf(fmaxf(s_wm[h], s_wm[16 + h]),
                          fmaxf(s_wm[32 + h], s_wm[48 + h]));

    const int k0 = tid >> 4;
    float a0 = 0.f, a1 = 0.f;
    #pragma unroll
    for (int f = 0; f < NFG; ++f) {
        a0 += __expf(s_ac[k0 * 64 + f * 16 + h] - m)        * s_gw[k0 * 4 + f];
        a1 += __expf(s_ac[(k0 + 16) * 64 + f * 16 + h] - m) * s_gw[(k0 + 16) * 4 + f];
    }

    float ls = fabsf(a0) + fabsf(a1);
    ls += __shfl_xor(ls, 16, 64);
    ls += __shfl_xor(ls, 32, 64);
    if (lane < 16) s_wd[wv * 16 + lane] = ls;
    __syncthreads();
    const float den = s_wd[h] + s_wd[16 + h] + s_wd[32 + h] + s_wd[48 + h] + EPS;

    attn_out[blz * KN + tid]       = a0 / den;   // k0*16+h == tid
    attn_out[blz * KN + tid + 256] = a1 / den;
}

// ---------------- K2: pure-streaming einsum ----------------
// out[row, p] = sum_k no[row*16384 + k*512 + p] * attn[row*512 + k*16 + (p&15)]
// 2 rows per block; thread owns one float4 output; 32-deep k loop.
__global__ __launch_bounds__(256, 8)
void einsum_k(const float* __restrict__ no,
              const float* __restrict__ attn,
              float* __restrict__ out)
{
    const int tid = threadIdx.x;
    const int r   = tid >> 7;                 // 0/1 within block
    const int u   = tid & 127;
    const int p   = u * 4;
    const int row = blockIdx.x * 2 + r;

    __shared__ float s_attn[2 * KN];          // 2 rows x 512

    // stage both rows' attn: one fully-coalesced float4 per thread
    *reinterpret_cast<float4*>(&s_attn[r * KN + p]) =
        *reinterpret_cast<const float4*>(attn + (size_t)row * KN + p);
    __syncthreads();

    const float*  basep = no + (size_t)row * ROWSTRIDE + p;
    const float*  wbase = &s_attn[r * KN + (p & 15)];

    float4 acc = make_float4(0.f, 0.f, 0.f, 0.f);
    #pragma unroll 4
    for (int k = 0; k < KNB; ++k) {
        const float4 v = *reinterpret_cast<const float4*>(basep + k * ON);
        const float4 w = *reinterpret_cast<const float4*>(wbase + k * NH);
        acc.x += v.x * w.x;
        acc.y += v.y * w.y;
        acc.z += v.z * w.z;
        acc.w += v.w * w.w;
    }
    *reinterpret_cast<float4*>(out + (size_t)row * ON + p) = acc;
}

extern "C" void kernel_launch(void* const* d_in, const int* in_sizes, int n_in,
                              void* d_out, int out_size, void* d_ws, size_t ws_size,
                              hipStream_t stream) {
    const float* beta = (const float*)d_in[0];
    const float* sa   = (const float*)d_in[1];
    const float* ac   = (const float*)d_in[2];
    const float* no   = (const float*)d_in[3];
    const float* gw   = (const float*)d_in[4];

    const int BL = in_sizes[0] / FH;   // B*L = 4096
    float* out      = (float*)d_out;
    float* attn_out = out + (size_t)BL * ON;

    attn_weights<<<BL, 256, 0, stream>>>(beta, sa, ac, gw, attn_out);
    einsum_k<<<BL / 2, 256, 0, stream>>>(no, attn_out, out);
}